// Round 5
// baseline (443.923 us; speedup 1.0000x reference)
//
#include <hip/hip_runtime.h>

// Round 5: bf16 gather tables + fused gather/transform kernels + merged
// T/I build chain.
//  - CSR build: bucket (dst>>7) bin + per-bucket LDS counting sort; both edge
//    types in one launch each (gridDim.y=2). start[] has sentinel start[N]=E
//    so degree = start[n+1]-start[n] (no deg arrays).
//  - L1: k_g1c1, block=128 nodes: gather bf16 x-rows (16B) from L2-resident
//    1.6MB table -> LDS sums -> 6->32 transforms -> h1 fp32 (residual) +
//    h1 bf16 (gather table).
//  - L2: k_g2c2cls, block=32 nodes: gather bf16 h1-rows (64B) -> LDS ->
//    three 32x32 transforms + relu + 32->7 classifier, out written directly.

#define BLK 256
#define RN 128
#define KMAX 1024

__device__ inline unsigned short f2bf(float f) {
  unsigned u = __float_as_uint(f);
  return (unsigned short)((u + 0x7FFFu + ((u >> 16) & 1u)) >> 16);
}
__device__ inline float bf2f(unsigned short h) {
  return __uint_as_float(((unsigned)h) << 16);
}

// ---------------- bucket build (both types per launch) ----------------
__global__ __launch_bounds__(BLK) void k_bhist2(
    const int* __restrict__ eiT, int ET, int* __restrict__ ghT,
    const int* __restrict__ eiI, int EI, int* __restrict__ ghI, int K) {
  const int* ei = blockIdx.y ? eiI : eiT;
  int E = blockIdx.y ? EI : ET;
  int* gh = blockIdx.y ? ghI : ghT;
  __shared__ int lh[KMAX];
  int t = threadIdx.x;
  for (int i = t; i < K; i += BLK) lh[i] = 0;
  __syncthreads();
  int nb = gridDim.x;
  int chunk = (E + nb - 1) / nb;
  int cs = blockIdx.x * chunk;
  int ce = min(E, cs + chunk);
  for (int e = cs + t; e < ce; e += BLK) atomicAdd(&lh[ei[E + e] >> 7], 1);
  __syncthreads();
  for (int b = t; b < K; b += BLK)
    if (lh[b]) atomicAdd(&gh[b], lh[b]);
}

__global__ __launch_bounds__(1024) void k_bscan2(
    const int* __restrict__ ghT, int* __restrict__ bsT, int* __restrict__ curT,
    int* __restrict__ startT, const int* __restrict__ ghI,
    int* __restrict__ bsI, int* __restrict__ curI, int* __restrict__ startI,
    int K, int N) {
  const int* gh = blockIdx.x ? ghI : ghT;
  int* bs  = blockIdx.x ? bsI : bsT;
  int* cur = blockIdx.x ? curI : curT;
  int* start = blockIdx.x ? startI : startT;
  __shared__ int s[1024];
  int t = threadIdx.x;
  int v = (t < K) ? gh[t] : 0;
  s[t] = v;
  __syncthreads();
  for (int off = 1; off < 1024; off <<= 1) {
    int x = (t >= off) ? s[t - off] : 0;
    __syncthreads();
    s[t] += x;
    __syncthreads();
  }
  if (t < K) {
    int excl = s[t] - v;
    bs[t] = excl;
    cur[t] = excl;
    if (t == K - 1) {
      bs[K] = s[t];
      start[N] = s[t];  // sentinel: deg[n] = start[n+1]-start[n]
    }
  }
}

__global__ __launch_bounds__(BLK) void k_bin2(
    const int* __restrict__ eiT, int ET, int* __restrict__ curT,
    int* __restrict__ binT, const int* __restrict__ eiI, int EI,
    int* __restrict__ curI, int* __restrict__ binI, int K) {
  const int* ei = blockIdx.y ? eiI : eiT;
  int E = blockIdx.y ? EI : ET;
  int* cur = blockIdx.y ? curI : curT;
  int* binned = blockIdx.y ? binI : binT;
  __shared__ int lh[KMAX];
  int t = threadIdx.x;
  for (int i = t; i < K; i += BLK) lh[i] = 0;
  __syncthreads();
  int nb = gridDim.x;
  int chunk = (E + nb - 1) / nb;
  int cs = blockIdx.x * chunk;
  int ce = min(E, cs + chunk);
  for (int e = cs + t; e < ce; e += BLK) atomicAdd(&lh[ei[E + e] >> 7], 1);
  __syncthreads();
  for (int b = t; b < K; b += BLK) {
    int c = lh[b];
    lh[b] = c ? atomicAdd(&cur[b], c) : 0;
  }
  __syncthreads();
  for (int e = cs + t; e < ce; e += BLK) {
    int src = ei[e];
    int d = ei[E + e];
    int pos = atomicAdd(&lh[d >> 7], 1);
    binned[pos] = (src << 7) | (d & 127);
  }
}

__global__ __launch_bounds__(BLK) void k_sortcsr2(
    const int* __restrict__ binT, const int* __restrict__ bsT,
    int* __restrict__ csrT, int* __restrict__ startT,
    const int* __restrict__ binI, const int* __restrict__ bsI,
    int* __restrict__ csrI, int* __restrict__ startI, int N) {
  const int* binned = blockIdx.y ? binI : binT;
  const int* bs = blockIdx.y ? bsI : bsT;
  int* csr = blockIdx.y ? csrI : csrT;
  int* start = blockIdx.y ? startI : startT;
  __shared__ int h[RN], s[RN], cur[RN];
  int t = threadIdx.x, b = blockIdx.x;
  if (t < RN) h[t] = 0;
  __syncthreads();
  int e0 = bs[b], e1 = bs[b + 1];
  for (int i = e0 + t; i < e1; i += BLK) atomicAdd(&h[binned[i] & 127], 1);
  __syncthreads();
  if (t < RN) s[t] = h[t];
  __syncthreads();
  for (int off = 1; off < RN; off <<= 1) {
    int v = 0;
    if (t < RN && t >= off) v = s[t - off];
    __syncthreads();
    if (t < RN) s[t] += v;
    __syncthreads();
  }
  if (t < RN) {
    int excl = s[t] - h[t];
    int n = b * RN + t;
    if (n < N) start[n] = e0 + excl;
    cur[t] = excl;
  }
  __syncthreads();
  for (int i = e0 + t; i < e1; i += BLK) {
    int p = binned[i];
    int pos = atomicAdd(&cur[p & 127], 1);
    csr[e0 + pos] = p >> 7;
  }
}

// ---------------- prep: x -> bf16 padded rows (8 ch) ----------------
__global__ __launch_bounds__(BLK) void k_prep(const float* __restrict__ x,
                                              unsigned short* __restrict__ xp,
                                              int N) {
  int gid = blockIdx.x * BLK + threadIdx.x;
  if (gid >= N * 8) return;
  int n = gid >> 3, c = gid & 7;
  xp[gid] = (c < 6) ? f2bf(x[n * 6 + c]) : (unsigned short)0;
}

// ---------------- fused layer 1: gather x + transform ----------------
// block = 128 nodes, 2 threads/node (4 bf16 = 8B per thread per edge)
__global__ __launch_bounds__(BLK) void k_g1c1(
    const unsigned short* __restrict__ xp, const float* __restrict__ x,
    const int* __restrict__ startT, const int* __restrict__ csrT,
    const int* __restrict__ startI, const int* __restrict__ csrI,
    const float* __restrict__ Wt, const float* __restrict__ bt,
    const float* __restrict__ Wi, const float* __restrict__ bi,
    const float* __restrict__ Wr, const float* __restrict__ br,
    float* __restrict__ h1f, unsigned short* __restrict__ h1b, int N) {
  __shared__ float sGT[RN * 8], sGI[RN * 8], sx[RN * 6];
  __shared__ float sWt[192], sWi[192], sWr[192], sb[96];
  __shared__ float sdT[RN], sdI[RN];
  int t = threadIdx.x, b = blockIdx.x;
  if (t < 192) { sWt[t] = Wt[t]; sWi[t] = Wi[t]; sWr[t] = Wr[t]; }
  if (t < 32) { sb[t] = bt[t]; sb[32 + t] = bi[t]; sb[64 + t] = br[t]; }
  for (int i = t; i < RN * 6; i += BLK) {
    int g = b * RN * 6 + i;
    sx[i] = (g < N * 6) ? x[g] : 0.0f;
  }
  int nl = t >> 1, sub = t & 1;
  int n = b * RN + nl;
  float a0 = 0.f, a1 = 0.f, a2 = 0.f, a3 = 0.f;
  float c0 = 0.f, c1 = 0.f, c2 = 0.f, c3 = 0.f;
  int dT = 0, dI = 0;
  if (n < N) {
    {
      int s0 = startT[n], s1 = startT[n + 1];
      dT = s1 - s0;
      for (int i = s0; i < s1; ++i) {
        int src = csrT[i];
        ushort4 v = *(const ushort4*)(xp + (size_t)src * 8 + sub * 4);
        a0 += bf2f(v.x); a1 += bf2f(v.y); a2 += bf2f(v.z); a3 += bf2f(v.w);
      }
    }
    {
      int s0 = startI[n], s1 = startI[n + 1];
      dI = s1 - s0;
      for (int i = s0; i < s1; ++i) {
        int src = csrI[i];
        ushort4 v = *(const ushort4*)(xp + (size_t)src * 8 + sub * 4);
        c0 += bf2f(v.x); c1 += bf2f(v.y); c2 += bf2f(v.z); c3 += bf2f(v.w);
      }
    }
  }
  int base = nl * 8 + sub * 4;
  sGT[base + 0] = a0; sGT[base + 1] = a1; sGT[base + 2] = a2; sGT[base + 3] = a3;
  sGI[base + 0] = c0; sGI[base + 1] = c1; sGI[base + 2] = c2; sGI[base + 3] = c3;
  if (sub == 0) { sdT[nl] = (float)dT; sdI[nl] = (float)dI; }
  __syncthreads();
  for (int idx = t; idx < RN * 32; idx += BLK) {
    int m = idx >> 5, j = idx & 31;
    int nn = b * RN + m;
    if (nn >= N) break;
    float fdT = sdT[m], fdI = sdI[m];
    float invI = 1.0f / fmaxf(fdI, 1.0f);
    float gate = (fdI > 0.0f) ? 1.0f : 0.0f;
    float acc = fdT * sb[j] + gate * sb[32 + j] + sb[64 + j];
#pragma unroll
    for (int k = 0; k < 6; ++k) {
      acc += sGT[m * 8 + k] * sWt[k * 32 + j];
      acc += sGI[m * 8 + k] * invI * sWi[k * 32 + j];
      acc += sx[m * 6 + k] * sWr[k * 32 + j];
    }
    acc = fmaxf(acc, 0.0f);
    h1f[(size_t)nn * 32 + j] = acc;
    h1b[(size_t)nn * 32 + j] = f2bf(acc);
  }
}

// ---------------- fused layer 2 + classifier ----------------
// block = 32 nodes, 8 threads/node (4 bf16 = 8B per thread per edge)
__global__ __launch_bounds__(BLK) void k_g2c2cls(
    const unsigned short* __restrict__ h1b, const float* __restrict__ h1f,
    const int* __restrict__ startT, const int* __restrict__ csrT,
    const int* __restrict__ startI, const int* __restrict__ csrI,
    const float* __restrict__ Wt, const float* __restrict__ bt,
    const float* __restrict__ Wi, const float* __restrict__ bi,
    const float* __restrict__ Wr, const float* __restrict__ br,
    const float* __restrict__ Wc, const float* __restrict__ bc,
    float* __restrict__ out, int N) {
  __shared__ float sWt[1024], sWi[1024], sWr[1024], sWc[224];
  __shared__ float sb[96], sbc[7];
  __shared__ float aggT[32 * 32], aggI[32 * 32], hR[32 * 32], h2[32 * 32];
  __shared__ float sdT[32], sdI[32];
  int t = threadIdx.x, b = blockIdx.x;
  for (int i = t; i < 1024; i += BLK) {
    sWt[i] = Wt[i];
    sWi[i] = Wi[i];
    sWr[i] = Wr[i];
    int g = b * 1024 + i;
    hR[i] = (g < N * 32) ? h1f[g] : 0.0f;
  }
  if (t < 224) sWc[t] = Wc[t];
  if (t < 32) { sb[t] = bt[t]; sb[32 + t] = bi[t]; sb[64 + t] = br[t]; }
  if (t < 7) sbc[t] = bc[t];
  int nl = t >> 3, sub = t & 7;
  int n = b * 32 + nl;
  float a0 = 0.f, a1 = 0.f, a2 = 0.f, a3 = 0.f;
  float c0 = 0.f, c1 = 0.f, c2 = 0.f, c3 = 0.f;
  int dT = 0, dI = 0;
  if (n < N) {
    {
      int s0 = startT[n], s1 = startT[n + 1];
      dT = s1 - s0;
      for (int i = s0; i < s1; ++i) {
        int src = csrT[i];
        ushort4 v = *(const ushort4*)(h1b + (size_t)src * 32 + sub * 4);
        a0 += bf2f(v.x); a1 += bf2f(v.y); a2 += bf2f(v.z); a3 += bf2f(v.w);
      }
    }
    {
      int s0 = startI[n], s1 = startI[n + 1];
      dI = s1 - s0;
      for (int i = s0; i < s1; ++i) {
        int src = csrI[i];
        ushort4 v = *(const ushort4*)(h1b + (size_t)src * 32 + sub * 4);
        c0 += bf2f(v.x); c1 += bf2f(v.y); c2 += bf2f(v.z); c3 += bf2f(v.w);
      }
    }
  }
  int base = nl * 32 + sub * 4;
  aggT[base + 0] = a0; aggT[base + 1] = a1; aggT[base + 2] = a2; aggT[base + 3] = a3;
  aggI[base + 0] = c0; aggI[base + 1] = c1; aggI[base + 2] = c2; aggI[base + 3] = c3;
  if (sub == 0) { sdT[nl] = (float)dT; sdI[nl] = (float)dI; }
  __syncthreads();
#pragma unroll
  for (int it = 0; it < 4; ++it) {
    int idx = t + it * BLK;
    int m = idx >> 5, j = idx & 31;
    int nn = b * 32 + m;
    float fdT = sdT[m], fdI = sdI[m];
    float invI = 1.0f / fmaxf(fdI, 1.0f);
    float gate = (fdI > 0.0f) ? 1.0f : 0.0f;
    float acc = fdT * sb[j] + gate * sb[32 + j] + sb[64 + j];
#pragma unroll
    for (int k = 0; k < 32; ++k) {
      acc += aggT[m * 32 + k] * sWt[k * 32 + j];
      acc += aggI[m * 32 + k] * invI * sWi[k * 32 + j];
      acc += hR[m * 32 + k] * sWr[k * 32 + j];
    }
    h2[idx] = (nn < N) ? fmaxf(acc, 0.0f) : 0.0f;
  }
  __syncthreads();
  if (t < 224) {
    int m = t / 7, j = t - m * 7;
    int nn = b * 32 + m;
    if (nn < N) {
      float a = sbc[j];
#pragma unroll
      for (int k = 0; k < 32; ++k) a += h2[m * 32 + k] * sWc[k * 7 + j];
      out[(size_t)nn * 7 + j] = a;
    }
  }
}

extern "C" void kernel_launch(void* const* d_in, const int* in_sizes, int n_in,
                              void* d_out, int out_size, void* d_ws,
                              size_t ws_size, hipStream_t stream) {
  const float* x   = (const float*)d_in[0];
  const int* ei_t  = (const int*)d_in[1];
  const int* ei_i  = (const int*)d_in[2];
  const float* W1t = (const float*)d_in[3];
  const float* b1t = (const float*)d_in[4];
  const float* W1i = (const float*)d_in[5];
  const float* b1i = (const float*)d_in[6];
  const float* W1r = (const float*)d_in[7];
  const float* b1r = (const float*)d_in[8];
  const float* W2t = (const float*)d_in[9];
  const float* b2t = (const float*)d_in[10];
  const float* W2i = (const float*)d_in[11];
  const float* b2i = (const float*)d_in[12];
  const float* W2r = (const float*)d_in[13];
  const float* b2r = (const float*)d_in[14];
  const float* Wc  = (const float*)d_in[15];
  const float* bc  = (const float*)d_in[16];
  float* out = (float*)d_out;

  const int N  = in_sizes[0] / 6;
  const int E  = in_sizes[1] / 2;
  const int Ei = in_sizes[2] / 2;
  const int K  = (N + RN - 1) / RN;

  float* h1f = (float*)d_ws;                        // N*32 fp32
  unsigned short* h1b = (unsigned short*)(h1f + (size_t)N * 32);  // N*32 bf16
  unsigned short* xp  = h1b + (size_t)N * 32;       // N*8 bf16
  int* ghistT = (int*)(xp + (size_t)N * 8);
  int* ghistI = ghistT + KMAX;
  int* bsT    = ghistI + KMAX;
  int* bsI    = bsT + (KMAX + 1);
  int* curT   = bsI + (KMAX + 1);
  int* curI   = curT + KMAX;
  int* startT = curI + KMAX;
  int* startI = startT + (N + 1);
  int* binT   = startI + (N + 1);
  int* binI   = binT + E;
  int* csrT   = binI + Ei;
  int* csrI   = csrT + E;

  const int gN8 = (N * 8 + BLK - 1) / BLK;
  const int NB  = 128;

  // ---- CSR build ----
  hipMemsetAsync(ghistT, 0, (size_t)2 * KMAX * sizeof(int), stream);
  k_bhist2<<<dim3(NB, 2), BLK, 0, stream>>>(ei_t, E, ghistT, ei_i, Ei, ghistI, K);
  k_bscan2<<<2, 1024, 0, stream>>>(ghistT, bsT, curT, startT, ghistI, bsI,
                                   curI, startI, K, N);
  k_bin2<<<dim3(NB, 2), BLK, 0, stream>>>(ei_t, E, curT, binT, ei_i, Ei, curI,
                                          binI, K);
  k_sortcsr2<<<dim3(K, 2), BLK, 0, stream>>>(binT, bsT, csrT, startT, binI,
                                             bsI, csrI, startI, N);

  // ---- Layer 1 ----
  k_prep<<<gN8, BLK, 0, stream>>>(x, xp, N);
  k_g1c1<<<K, BLK, 0, stream>>>(xp, x, startT, csrT, startI, csrI, W1t, b1t,
                                W1i, b1i, W1r, b1r, h1f, h1b, N);

  // ---- Layer 2 + classifier ----
  k_g2c2cls<<<(N + 31) / 32, BLK, 0, stream>>>(h1b, h1f, startT, csrT, startI,
                                               csrI, W2t, b2t, W2i, b2i, W2r,
                                               b2r, Wc, bc, out, N);
}

// Round 6
// 325.247 us; speedup vs baseline: 1.3649x; 1.3649x over previous
//
#include <hip/hip_runtime.h>

// Round 6: bf16 gather tables + SPLIT high-occupancy gather2 (round-5 fusion
// killed occupancy 61%->29% and throughput 2.6TB/s->0.64TB/s) + padded-bucket
// build (no bhist/bscan; csr sorts in place over bin).
//
// ws: h1f[N*32] aggT[N*32] aggI[N*32] (f32) | h1b[N*32] xp[N*8] (bf16) |
//     curT curI [KMAX] | startT degT startI degI [N] | binT binI [K*CAP]

#define BLK 256
#define RN 128
#define KMAX 1024
#define CAP 3008

typedef unsigned short us8 __attribute__((ext_vector_type(8)));

__device__ inline unsigned short f2bf(float f) {
  unsigned u = __float_as_uint(f);
  return (unsigned short)((u + 0x7FFFu + ((u >> 16) & 1u)) >> 16);
}
__device__ inline float bf2f(unsigned short h) {
  return __uint_as_float(((unsigned)h) << 16);
}

// ---------------- build ----------------
__global__ __launch_bounds__(1024) void k_init(int* __restrict__ curT,
                                               int* __restrict__ curI, int K) {
  int t = threadIdx.x;
  for (int i = t; i < K; i += 1024) {
    curT[i] = i * CAP;
    curI[i] = i * CAP;
  }
}

// bin edges into padded buckets (dst>>7): LDS hist -> global reserve -> write
__global__ __launch_bounds__(BLK) void k_bin2p(
    const int* __restrict__ eiT, int ET, int* __restrict__ curT,
    int* __restrict__ binT, const int* __restrict__ eiI, int EI,
    int* __restrict__ curI, int* __restrict__ binI, int K) {
  const int* ei = blockIdx.y ? eiI : eiT;
  int E = blockIdx.y ? EI : ET;
  int* cur = blockIdx.y ? curI : curT;
  int* binned = blockIdx.y ? binI : binT;
  __shared__ int lh[KMAX];
  int t = threadIdx.x;
  for (int i = t; i < K; i += BLK) lh[i] = 0;
  __syncthreads();
  int nb = gridDim.x;
  int chunk = (E + nb - 1) / nb;
  int cs = blockIdx.x * chunk;
  int ce = min(E, cs + chunk);
  for (int e = cs + t; e < ce; e += BLK) atomicAdd(&lh[ei[E + e] >> 7], 1);
  __syncthreads();
  for (int b = t; b < K; b += BLK) {
    int c = lh[b];
    lh[b] = c ? atomicAdd(&cur[b], c) : 0;
  }
  __syncthreads();
  for (int e = cs + t; e < ce; e += BLK) {
    int src = ei[e];
    int d = ei[E + e];
    int pos = atomicAdd(&lh[d >> 7], 1);
    binned[pos] = (src << 7) | (d & 127);
  }
}

// per-bucket counting sort, in place (stage bucket in LDS), emit start/deg
__global__ __launch_bounds__(BLK) void k_sortcsr2p(
    int* __restrict__ binT, const int* __restrict__ curT,
    int* __restrict__ startT, int* __restrict__ degT, int* __restrict__ binI,
    const int* __restrict__ curI, int* __restrict__ startI,
    int* __restrict__ degI, int N) {
  int* bin = blockIdx.y ? binI : binT;
  const int* cur = blockIdx.y ? curI : curT;
  int* start = blockIdx.y ? startI : startT;
  int* deg = blockIdx.y ? degI : degT;
  __shared__ int ebuf[CAP];
  __shared__ int h[RN], s[RN], c2[RN];
  int t = threadIdx.x, b = blockIdx.x;
  int e0 = b * CAP;
  int cnt = min(cur[b] - e0, CAP);
  if (t < RN) h[t] = 0;
  __syncthreads();
  for (int i = t; i < cnt; i += BLK) {
    int p = bin[e0 + i];
    ebuf[i] = p;
    atomicAdd(&h[p & 127], 1);
  }
  __syncthreads();
  if (t < RN) s[t] = h[t];
  __syncthreads();
  for (int off = 1; off < RN; off <<= 1) {
    int v = 0;
    if (t < RN && t >= off) v = s[t - off];
    __syncthreads();
    if (t < RN) s[t] += v;
    __syncthreads();
  }
  if (t < RN) {
    int excl = s[t] - h[t];
    int n = b * RN + t;
    if (n < N) {
      start[n] = e0 + excl;
      deg[n] = h[t];
    }
    c2[t] = excl;
  }
  __syncthreads();
  for (int i = t; i < cnt; i += BLK) {
    int p = ebuf[i];
    int pos = atomicAdd(&c2[p & 127], 1);
    bin[e0 + pos] = p >> 7;
  }
}

// ---------------- prep: x -> bf16 padded rows (8 ch) ----------------
__global__ __launch_bounds__(BLK) void k_prep(const float* __restrict__ x,
                                              unsigned short* __restrict__ xp,
                                              int N) {
  int gid = blockIdx.x * BLK + threadIdx.x;
  if (gid >= N * 8) return;
  int n = gid >> 3, c = gid & 7;
  xp[gid] = (c < 6) ? f2bf(x[n * 6 + c]) : (unsigned short)0;
}

// ---------------- fused layer 1: gather x + transform ----------------
__global__ __launch_bounds__(BLK) void k_g1c1(
    const unsigned short* __restrict__ xp, const float* __restrict__ x,
    const int* __restrict__ startT, const int* __restrict__ degT,
    const int* __restrict__ csrT, const int* __restrict__ startI,
    const int* __restrict__ degI, const int* __restrict__ csrI,
    const float* __restrict__ Wt, const float* __restrict__ bt,
    const float* __restrict__ Wi, const float* __restrict__ bi,
    const float* __restrict__ Wr, const float* __restrict__ br,
    float* __restrict__ h1f, unsigned short* __restrict__ h1b, int N) {
  __shared__ float sGT[RN * 8], sGI[RN * 8], sx[RN * 6];
  __shared__ float sWt[192], sWi[192], sWr[192], sb[96];
  __shared__ float sdT[RN], sdI[RN];
  int t = threadIdx.x, b = blockIdx.x;
  if (t < 192) { sWt[t] = Wt[t]; sWi[t] = Wi[t]; sWr[t] = Wr[t]; }
  if (t < 32) { sb[t] = bt[t]; sb[32 + t] = bi[t]; sb[64 + t] = br[t]; }
  for (int i = t; i < RN * 6; i += BLK) {
    int g = b * RN * 6 + i;
    sx[i] = (g < N * 6) ? x[g] : 0.0f;
  }
  int nl = t >> 1, sub = t & 1;
  int n = b * RN + nl;
  float a0 = 0.f, a1 = 0.f, a2 = 0.f, a3 = 0.f;
  float c0 = 0.f, c1 = 0.f, c2 = 0.f, c3 = 0.f;
  int dT = 0, dI = 0;
  if (n < N) {
    {
      int s0 = startT[n];
      dT = degT[n];
      const int* c = csrT + s0;
      for (int i = 0; i < dT; ++i) {
        int src = c[i];
        ushort4 v = *(const ushort4*)(xp + (size_t)src * 8 + sub * 4);
        a0 += bf2f(v.x); a1 += bf2f(v.y); a2 += bf2f(v.z); a3 += bf2f(v.w);
      }
    }
    {
      int s0 = startI[n];
      dI = degI[n];
      const int* c = csrI + s0;
      for (int i = 0; i < dI; ++i) {
        int src = c[i];
        ushort4 v = *(const ushort4*)(xp + (size_t)src * 8 + sub * 4);
        c0 += bf2f(v.x); c1 += bf2f(v.y); c2 += bf2f(v.z); c3 += bf2f(v.w);
      }
    }
  }
  int base = nl * 8 + sub * 4;
  sGT[base + 0] = a0; sGT[base + 1] = a1; sGT[base + 2] = a2; sGT[base + 3] = a3;
  sGI[base + 0] = c0; sGI[base + 1] = c1; sGI[base + 2] = c2; sGI[base + 3] = c3;
  if (sub == 0) { sdT[nl] = (float)dT; sdI[nl] = (float)dI; }
  __syncthreads();
  for (int idx = t; idx < RN * 32; idx += BLK) {
    int m = idx >> 5, j = idx & 31;
    int nn = b * RN + m;
    if (nn >= N) break;
    float fdT = sdT[m], fdI = sdI[m];
    float invI = 1.0f / fmaxf(fdI, 1.0f);
    float gate = (fdI > 0.0f) ? 1.0f : 0.0f;
    float acc = fdT * sb[j] + gate * sb[32 + j] + sb[64 + j];
#pragma unroll
    for (int k = 0; k < 6; ++k) {
      acc += sGT[m * 8 + k] * sWt[k * 32 + j];
      acc += sGI[m * 8 + k] * invI * sWi[k * 32 + j];
      acc += sx[m * 6 + k] * sWr[k * 32 + j];
    }
    acc = fmaxf(acc, 0.0f);
    h1f[(size_t)nn * 32 + j] = acc;
    h1b[(size_t)nn * 32 + j] = f2bf(acc);
  }
}

// ---------------- layer-2 gather: 4 thr/node, 16B bf16 loads, y=edge type ---
__global__ __launch_bounds__(BLK) void k_gather2(
    const unsigned short* __restrict__ h1b, const int* __restrict__ startT,
    const int* __restrict__ degT, const int* __restrict__ csrT,
    const int* __restrict__ startI, const int* __restrict__ degI,
    const int* __restrict__ csrI, float* __restrict__ aggT,
    float* __restrict__ aggI, int N) {
  const int* start = blockIdx.y ? startI : startT;
  const int* deg = blockIdx.y ? degI : degT;
  const int* csr = blockIdx.y ? csrI : csrT;
  float* agg = blockIdx.y ? aggI : aggT;
  int gid = blockIdx.x * BLK + threadIdx.x;
  int n = gid >> 2;
  if (n >= N) return;
  int sub = gid & 3;
  float a0 = 0.f, a1 = 0.f, a2 = 0.f, a3 = 0.f;
  float a4 = 0.f, a5 = 0.f, a6 = 0.f, a7 = 0.f;
  int s0 = start[n], d = deg[n];
  const int* c = csr + s0;
  int i = 0;
  for (; i + 2 <= d; i += 2) {
    int src0 = c[i], src1 = c[i + 1];
    us8 v0 = *(const us8*)(h1b + (size_t)src0 * 32 + sub * 8);
    us8 v1 = *(const us8*)(h1b + (size_t)src1 * 32 + sub * 8);
    a0 += bf2f(v0[0]) + bf2f(v1[0]);
    a1 += bf2f(v0[1]) + bf2f(v1[1]);
    a2 += bf2f(v0[2]) + bf2f(v1[2]);
    a3 += bf2f(v0[3]) + bf2f(v1[3]);
    a4 += bf2f(v0[4]) + bf2f(v1[4]);
    a5 += bf2f(v0[5]) + bf2f(v1[5]);
    a6 += bf2f(v0[6]) + bf2f(v1[6]);
    a7 += bf2f(v0[7]) + bf2f(v1[7]);
  }
  if (i < d) {
    int src0 = c[i];
    us8 v0 = *(const us8*)(h1b + (size_t)src0 * 32 + sub * 8);
    a0 += bf2f(v0[0]); a1 += bf2f(v0[1]); a2 += bf2f(v0[2]); a3 += bf2f(v0[3]);
    a4 += bf2f(v0[4]); a5 += bf2f(v0[5]); a6 += bf2f(v0[6]); a7 += bf2f(v0[7]);
  }
  float4 o0 = {a0, a1, a2, a3}, o1 = {a4, a5, a6, a7};
  float* p = agg + (size_t)n * 32 + sub * 8;
  *(float4*)p = o0;
  *(float4*)(p + 4) = o1;
}

// ---------------- combine2 + classifier (round-4 structure) ----------------
__global__ __launch_bounds__(BLK) void k_combine2cls(
    const float* __restrict__ aggT, const float* __restrict__ aggI,
    const float* __restrict__ h1, const int* __restrict__ degT,
    const int* __restrict__ degI, const float* __restrict__ Wt,
    const float* __restrict__ bt, const float* __restrict__ Wi,
    const float* __restrict__ bi, const float* __restrict__ Wr,
    const float* __restrict__ br, const float* __restrict__ Wc,
    const float* __restrict__ bc, float* __restrict__ out, int N) {
  __shared__ float sWt[1024], sWi[1024], sWr[1024], sWc[224];
  __shared__ float sb[96], sbc[7];
  __shared__ float hT[BLK], hI[BLK], hR[BLK], hs2[BLK];
  __shared__ float sdT[8], sdI[8];
  int t = threadIdx.x;
  for (int i = t; i < 1024; i += BLK) {
    sWt[i] = Wt[i];
    sWi[i] = Wi[i];
    sWr[i] = Wr[i];
  }
  if (t < 224) sWc[t] = Wc[t];
  if (t < 32) { sb[t] = bt[t]; sb[32 + t] = bi[t]; sb[64 + t] = br[t]; }
  if (t < 7) sbc[t] = bc[t];
  int gid = blockIdx.x * BLK + t;
  int nodeBase = (blockIdx.x * BLK) >> 5;
  if (gid < N * 32) {
    hT[t] = aggT[gid];
    hI[t] = aggI[gid];
    hR[t] = h1[gid];
  } else {
    hT[t] = 0.f; hI[t] = 0.f; hR[t] = 0.f;
  }
  if (t < 8) {
    int n = nodeBase + t;
    sdT[t] = (n < N) ? (float)degT[n] : 0.f;
    sdI[t] = (n < N) ? (float)degI[n] : 0.f;
  }
  __syncthreads();
  int j = t & 31, ln = t >> 5;
  float dT = sdT[ln], dI = sdI[ln];
  float invI = 1.0f / fmaxf(dI, 1.0f);
  float gate = (dI > 0.0f) ? 1.0f : 0.0f;
  float acc = dT * sb[j] + gate * sb[32 + j] + sb[64 + j];
#pragma unroll
  for (int k = 0; k < 32; ++k) {
    acc += hT[ln * 32 + k] * sWt[k * 32 + j];
    acc += hI[ln * 32 + k] * invI * sWi[k * 32 + j];
    acc += hR[ln * 32 + k] * sWr[k * 32 + j];
  }
  hs2[t] = fmaxf(acc, 0.0f);
  __syncthreads();
  if (j < 7) {
    int n = nodeBase + ln;
    if (n < N) {
      float a = sbc[j];
#pragma unroll
      for (int k = 0; k < 32; ++k) a += hs2[ln * 32 + k] * sWc[k * 7 + j];
      out[(size_t)n * 7 + j] = a;
    }
  }
}

extern "C" void kernel_launch(void* const* d_in, const int* in_sizes, int n_in,
                              void* d_out, int out_size, void* d_ws,
                              size_t ws_size, hipStream_t stream) {
  const float* x   = (const float*)d_in[0];
  const int* ei_t  = (const int*)d_in[1];
  const int* ei_i  = (const int*)d_in[2];
  const float* W1t = (const float*)d_in[3];
  const float* b1t = (const float*)d_in[4];
  const float* W1i = (const float*)d_in[5];
  const float* b1i = (const float*)d_in[6];
  const float* W1r = (const float*)d_in[7];
  const float* b1r = (const float*)d_in[8];
  const float* W2t = (const float*)d_in[9];
  const float* b2t = (const float*)d_in[10];
  const float* W2i = (const float*)d_in[11];
  const float* b2i = (const float*)d_in[12];
  const float* W2r = (const float*)d_in[13];
  const float* b2r = (const float*)d_in[14];
  const float* Wc  = (const float*)d_in[15];
  const float* bc  = (const float*)d_in[16];
  float* out = (float*)d_out;

  const int N  = in_sizes[0] / 6;
  const int E  = in_sizes[1] / 2;
  const int Ei = in_sizes[2] / 2;
  const int K  = (N + RN - 1) / RN;

  float* h1f  = (float*)d_ws;
  float* aggT = h1f + (size_t)N * 32;
  float* aggI = aggT + (size_t)N * 32;
  unsigned short* h1b = (unsigned short*)(aggI + (size_t)N * 32);
  unsigned short* xp  = h1b + (size_t)N * 32;
  int* curT   = (int*)(xp + (size_t)N * 8);
  int* curI   = curT + KMAX;
  int* startT = curI + KMAX;
  int* degT   = startT + N;
  int* startI = degT + N;
  int* degI   = startI + N;
  int* binT   = degI + N;
  int* binI   = binT + (size_t)K * CAP;

  const int gN8 = (N * 8 + BLK - 1) / BLK;
  const int gG2 = (N * 4 + BLK - 1) / BLK;
  const int gC2 = (N * 32 + BLK - 1) / BLK;
  const int NB  = 128;

  // ---- build (padded buckets; csr sorts in place over bin) ----
  k_init<<<1, 1024, 0, stream>>>(curT, curI, K);
  k_prep<<<gN8, BLK, 0, stream>>>(x, xp, N);
  k_bin2p<<<dim3(NB, 2), BLK, 0, stream>>>(ei_t, E, curT, binT, ei_i, Ei,
                                           curI, binI, K);
  k_sortcsr2p<<<dim3(K, 2), BLK, 0, stream>>>(binT, curT, startT, degT, binI,
                                              curI, startI, degI, N);

  // ---- Layer 1 (fused gather+transform) ----
  k_g1c1<<<K, BLK, 0, stream>>>(xp, x, startT, degT, binT, startI, degI, binI,
                                W1t, b1t, W1i, b1i, W1r, b1r, h1f, h1b, N);

  // ---- Layer 2 (split: high-occupancy gather, then combine+cls) ----
  k_gather2<<<dim3(gG2, 2), BLK, 0, stream>>>(h1b, startT, degT, binT, startI,
                                              degI, binI, aggT, aggI, N);
  k_combine2cls<<<gC2, BLK, 0, stream>>>(aggT, aggI, h1f, degT, degI, W2t,
                                         b2t, W2i, b2i, W2r, b2r, Wc, bc, out,
                                         N);
}